// Round 9
// baseline (5162.354 us; speedup 1.0000x reference)
//
#include <hip/hip_runtime.h>

#define SEQ_LEN 256
#define SPIKE_STEPS 7
#define T_TOTAL (SEQ_LEN * SPIKE_STEPS)
#define BATCH 128
#define IN_DIM 96
#define HIDDEN 512
#define OUT_DIM 2

// Weight buffers carry an extra all-zero row (index 512) used to pad the
// active list to a multiple of 16. Inner loop is a 3-deep software pipeline
// (48 outstanding loads < vmcnt cap 63) with rotation-by-branch (no copies).
#define WROWS (HIDDEN + 1)
#define GW 16                      // pipeline group width
#define ROWB (HIDDEN * 4)          // row stride in bytes (2048)

// d_ws layout: W0T [96*512] | W1T [513*512] | W2T [513*512] | ctr[128] | zbuf[B][T][8] u64
#define W0T_OFF 0
#define W1T_OFF (IN_DIM * HIDDEN)
#define W2T_OFF (W1T_OFF + WROWS * HIDDEN)
#define CTR_BYTE_OFF ((size_t)(W2T_OFF + WROWS * HIDDEN) * sizeof(float))
#define ZBUF_BYTE_OFF (CTR_BYTE_OFF + 1024)

__global__ void transpose_kernel(const float* __restrict__ in, float* __restrict__ out,
                                 int rows, int cols) {
    int idx = blockIdx.x * blockDim.x + threadIdx.x;
    if (idx < rows * cols) {
        int r = idx / cols, c = idx - r * cols;
        out[c * rows + r] = in[idx];
    }
}

// act[] holds wave-uniform BYTE offsets (j*2048); readfirstlane moves them to
// SGPRs so each load is s[base+off] + v(tid*4) — no per-lane 64-bit VGPR math.
__device__ __forceinline__ void load_group(const char* __restrict__ Wb,
                                           const int* __restrict__ act, int n,
                                           int tid4, float* b) {
    #pragma unroll
    for (int k = 0; k < GW; ++k) {
        int off = __builtin_amdgcn_readfirstlane(act[n + k]);
        b[k] = *(const float*)(Wb + off + tid4);
    }
}

#define CONSUME(B) { _Pragma("unroll") for (int k = 0; k < GW; ++k) cur = __fadd_rn(cur, (B)[k]); }

// Sum of active weight rows: 3-deep, 16-wide software pipeline, rotation via
// wave-uniform state branches (static buffer indices, zero copies). Add order
// = ascending act + trailing zero-rows => bit-identical to in-order sum.
__device__ __forceinline__ float row_sum_pipelined(const float* __restrict__ W,
                                                   const int* __restrict__ act,
                                                   int npad, int tid) {
    const char* Wb = (const char*)W;
    const int tid4 = tid * 4;
    float cur = 0.f;
    if (npad == 0) return cur;

    float b0[GW], b1[GW], b2[GW];
    load_group(Wb, act, 0, tid4, b0);
    if (npad == GW) { CONSUME(b0); return cur; }
    load_group(Wb, act, GW, tid4, b1);

    int st = 0;
    for (int n = 2 * GW; n < npad; n += GW) {
        if (st == 0)      { load_group(Wb, act, n, tid4, b2); CONSUME(b0); st = 1; }
        else if (st == 1) { load_group(Wb, act, n, tid4, b0); CONSUME(b1); st = 2; }
        else              { load_group(Wb, act, n, tid4, b1); CONSUME(b2); st = 0; }
    }
    if (st == 0)      { CONSUME(b0); CONSUME(b1); }
    else if (st == 1) { CONSUME(b1); CONSUME(b2); }
    else              { CONSUME(b2); CONSUME(b0); }
    return cur;
}

// Round-2 two-stage pipeline: even blocks = producer (layer0+layer1),
// odd = consumer (layer2+output); per-step mask handoff through L2 with
// relaxed agent-scope atomics.
__launch_bounds__(512, 1)
__global__ void snn_pipe_kernel(const float* __restrict__ x,     // [256,128,96]
                                const float* __restrict__ Wout,  // [2,512]
                                const float* __restrict__ betas, // [3]
                                const float* __restrict__ thrs,  // [3]
                                const float* __restrict__ W0T,   // [96,512]
                                const float* __restrict__ W1T,   // [513,512]
                                const float* __restrict__ W2T,   // [513,512]
                                unsigned long long* __restrict__ zbuf,
                                int* __restrict__ ctr,
                                float* __restrict__ out)         // [256,128,2]
{
    const int b    = blockIdx.x >> 1;
    const int role = blockIdx.x & 1;
    const int tid  = threadIdx.x;
    const int lane = tid & 63;
    const int wid  = tid >> 6;

    __shared__ float xs[IN_DIM];
    __shared__ unsigned long long zm[8];
    __shared__ int act[HIDDEN + GW];
    __shared__ float red[16];

    if (role == 0) {
        // ---------------- producer: layer0 + layer1 ----------------
        const float beta0 = betas[0], beta1 = betas[1];
        const float thr0  = thrs[0],  thr1  = thrs[1];
        float mem0 = 0.f, mem1 = 0.f;
        unsigned long long* zb = zbuf + (size_t)b * T_TOTAL * 8;

        for (int i = 0; i < SEQ_LEN; ++i) {
            if (tid < IN_DIM) xs[tid] = x[(i * BATCH + b) * IN_DIM + tid];
            __syncthreads();

            float cur0 = 0.f;
            #pragma unroll 8
            for (int k = 0; k < IN_DIM; ++k)
                cur0 = __fmaf_rn(xs[k], W0T[k * HIDDEN + tid], cur0);

            for (int s = 0; s < SPIKE_STEPS; ++s) {
                const int t = i * SPIKE_STEPS + s;

                // layer 0 LIF
                bool reset0 = (mem0 - thr0) > 0.f;
                mem0 = reset0 ? 0.f : __fadd_rn(__fmul_rn(beta0, mem0), cur0);
                bool z0 = (mem0 - thr0) > 0.f;
                unsigned long long bal = __ballot(z0);
                if (lane == 0) zm[wid] = bal;
                __syncthreads();

                int nact, npad;
                {
                    int pre = 0, total = 0;
                    #pragma unroll
                    for (int q = 0; q < 8; ++q) {
                        int p = __popcll(zm[q]);
                        total += p;
                        if (q < wid) pre += p;
                    }
                    int rank = pre + __popcll(zm[wid] & ((1ull << lane) - 1ull));
                    if (z0) act[rank] = tid * ROWB;                 // byte offset
                    nact = total;
                    npad = (nact + GW - 1) & ~(GW - 1);
                    if (tid < npad - nact) act[nact + tid] = HIDDEN * ROWB;  // zero-row pads
                }
                __syncthreads();

                float cur1 = row_sum_pipelined(W1T, act, npad, tid);

                // layer 1 LIF
                bool reset1 = (mem1 - thr1) > 0.f;
                mem1 = reset1 ? 0.f : __fadd_rn(__fmul_rn(beta1, mem1), cur1);
                bool z1 = (mem1 - thr1) > 0.f;

                unsigned long long bal1 = __ballot(z1);
                if (lane == 0)
                    __hip_atomic_store(&zb[(size_t)t * 8 + wid], bal1,
                                       __ATOMIC_RELAXED, __HIP_MEMORY_SCOPE_AGENT);
                __syncthreads();   // vmcnt(0) drain before barrier => masks visible
                if (tid == 0)
                    __hip_atomic_store(&ctr[b], t + 1,
                                       __ATOMIC_RELAXED, __HIP_MEMORY_SCOPE_AGENT);
            }
        }
    } else {
        // ---------------- consumer: layer2 + output ----------------
        const float beta2 = betas[2];
        const float thr2  = thrs[2];
        const float wo0 = Wout[tid];
        const float wo1 = Wout[HIDDEN + tid];
        float mem2 = 0.f, mo0 = 0.f, mo1 = 0.f;
        const unsigned long long* zb = zbuf + (size_t)b * T_TOTAL * 8;

        for (int i = 0; i < SEQ_LEN; ++i) {
            float so0 = 0.f, so1 = 0.f;

            for (int s = 0; s < SPIKE_STEPS; ++s) {
                const int t = i * SPIKE_STEPS + s;

                if (tid == 0) {
                    while (__hip_atomic_load(&ctr[b], __ATOMIC_RELAXED,
                                             __HIP_MEMORY_SCOPE_AGENT) < t + 1)
                        __builtin_amdgcn_s_sleep(1);
                }
                __syncthreads();

                if (tid < 8)
                    zm[tid] = __hip_atomic_load(&zb[(size_t)t * 8 + tid],
                                                __ATOMIC_RELAXED, __HIP_MEMORY_SCOPE_AGENT);
                __syncthreads();

                bool z1 = (zm[wid] >> lane) & 1ull;
                int nact, npad;
                {
                    int pre = 0, total = 0;
                    #pragma unroll
                    for (int q = 0; q < 8; ++q) {
                        int p = __popcll(zm[q]);
                        total += p;
                        if (q < wid) pre += p;
                    }
                    int rank = pre + __popcll(zm[wid] & ((1ull << lane) - 1ull));
                    if (z1) act[rank] = tid * ROWB;                 // byte offset
                    nact = total;
                    npad = (nact + GW - 1) & ~(GW - 1);
                    if (tid < npad - nact) act[nact + tid] = HIDDEN * ROWB;  // zero-row pads
                }
                __syncthreads();

                float cur2 = row_sum_pipelined(W2T, act, npad, tid);

                // layer 2 LIF
                bool reset2 = (mem2 - thr2) > 0.f;
                mem2 = reset2 ? 0.f : __fadd_rn(__fmul_rn(beta2, mem2), cur2);
                bool z2 = (mem2 - thr2) > 0.f;

                // output integrator
                float c0 = z2 ? wo0 : 0.f;
                float c1 = z2 ? wo1 : 0.f;
                #pragma unroll
                for (int off = 32; off > 0; off >>= 1) {
                    c0 += __shfl_down(c0, off);
                    c1 += __shfl_down(c1, off);
                }
                if (lane == 0) { red[wid * 2] = c0; red[wid * 2 + 1] = c1; }
                __syncthreads();
                if (tid == 0) {
                    float r0 = 0.f, r1 = 0.f;
                    #pragma unroll
                    for (int q = 0; q < 8; ++q) { r0 += red[q * 2]; r1 += red[q * 2 + 1]; }
                    mo0 += r0; mo1 += r1;
                    so0 += mo0; so1 += mo1;
                }
            }

            if (tid == 0) {
                out[(i * BATCH + b) * OUT_DIM + 0] = so0 / 7.0f;
                out[(i * BATCH + b) * OUT_DIM + 1] = so1 / 7.0f;
            }
        }
    }
}

extern "C" void kernel_launch(void* const* d_in, const int* in_sizes, int n_in,
                              void* d_out, int out_size, void* d_ws, size_t ws_size,
                              hipStream_t stream) {
    const float* x     = (const float*)d_in[0];
    const float* W0    = (const float*)d_in[1];
    const float* W1    = (const float*)d_in[2];
    const float* W2    = (const float*)d_in[3];
    const float* Wout  = (const float*)d_in[4];
    const float* betas = (const float*)d_in[5];
    const float* thrs  = (const float*)d_in[6];
    float* out = (float*)d_out;

    float* ws  = (float*)d_ws;
    float* W0T = ws + W0T_OFF;
    float* W1T = ws + W1T_OFF;
    float* W2T = ws + W2T_OFF;
    int* ctr = (int*)((char*)d_ws + CTR_BYTE_OFF);
    unsigned long long* zbuf = (unsigned long long*)((char*)d_ws + ZBUF_BYTE_OFF);

    {
        int n = HIDDEN * IN_DIM;
        transpose_kernel<<<(n + 255) / 256, 256, 0, stream>>>(W0, W0T, HIDDEN, IN_DIM);
    }
    {
        int n = HIDDEN * HIDDEN;
        transpose_kernel<<<(n + 255) / 256, 256, 0, stream>>>(W1, W1T, HIDDEN, HIDDEN);
        transpose_kernel<<<(n + 255) / 256, 256, 0, stream>>>(W2, W2T, HIDDEN, HIDDEN);
    }

    // zero the pad row (index 512) of W1T/W2T, and the progress counters
    hipMemsetAsync(W1T + (size_t)HIDDEN * HIDDEN, 0, HIDDEN * sizeof(float), stream);
    hipMemsetAsync(W2T + (size_t)HIDDEN * HIDDEN, 0, HIDDEN * sizeof(float), stream);
    hipMemsetAsync((char*)d_ws + CTR_BYTE_OFF, 0, 1024, stream);

    snn_pipe_kernel<<<2 * BATCH, HIDDEN, 0, stream>>>(
        x, Wout, betas, thrs, W0T, W1T, W2T, zbuf, ctr, out);
}

// Round 10
// 4494.720 us; speedup vs baseline: 1.1485x; 1.1485x over previous
//
#include <hip/hip_runtime.h>

#define SEQ_LEN 256
#define SPIKE_STEPS 7
#define T_TOTAL (SEQ_LEN * SPIKE_STEPS)
#define BATCH 128
#define IN_DIM 96
#define HIDDEN 512
#define OUT_DIM 2

#define WROWS (HIDDEN + 1)     // +1 zero row for padding
#define GW 16                  // pipeline group width (2-deep, 32 outstanding < 63 cap)

#define H_LDS 64                             // columns 448..511 served from LDS (wave 7)
#define H_GLB (HIDDEN - H_LDS)               // 448
#define LDS_DYN_BYTES (WROWS * H_LDS * 4)    // 513*64*4 = 131,328 B

// d_ws layout: W0T [96*512] | W1T [513*512] | W2T [513*512] | ctr[128] | zbuf[B][T][8] u64
#define W0T_OFF 0
#define W1T_OFF (IN_DIM * HIDDEN)
#define W2T_OFF (W1T_OFF + WROWS * HIDDEN)
#define CTR_BYTE_OFF ((size_t)(W2T_OFF + WROWS * HIDDEN) * sizeof(float))
#define ZBUF_BYTE_OFF (CTR_BYTE_OFF + 1024)

__global__ void transpose_kernel(const float* __restrict__ in, float* __restrict__ out,
                                 int rows, int cols) {
    int idx = blockIdx.x * blockDim.x + threadIdx.x;
    if (idx < rows * cols) {
        int r = idx / cols, c = idx - r * cols;
        out[c * rows + r] = in[idx];
    }
}

// Sum of active rows, global path (tid < 448): r7's proven depth-2 pipeline,
// with group indices fetched as 4x int4 (ds_read_b128) instead of 16x b32.
__device__ __forceinline__ float row_sum_glb(const float* __restrict__ W,
                                             const int* __restrict__ act,
                                             int npad, int tid) {
    float cur = 0.f;
    if (npad == 0) return cur;
    int idx[GW];
    float buf[GW];
    #pragma unroll
    for (int q = 0; q < GW / 4; ++q) {
        int4 v = *(const int4*)(&act[q * 4]);
        idx[q * 4] = v.x; idx[q * 4 + 1] = v.y; idx[q * 4 + 2] = v.z; idx[q * 4 + 3] = v.w;
    }
    #pragma unroll
    for (int k = 0; k < GW; ++k) buf[k] = W[idx[k] * HIDDEN + tid];
    for (int n = GW; n < npad; n += GW) {
        int nidx[GW];
        float nxt[GW];
        #pragma unroll
        for (int q = 0; q < GW / 4; ++q) {
            int4 v = *(const int4*)(&act[n + q * 4]);
            nidx[q * 4] = v.x; nidx[q * 4 + 1] = v.y; nidx[q * 4 + 2] = v.z; nidx[q * 4 + 3] = v.w;
        }
        #pragma unroll
        for (int k = 0; k < GW; ++k) nxt[k] = W[nidx[k] * HIDDEN + tid];
        #pragma unroll
        for (int k = 0; k < GW; ++k) cur = __fadd_rn(cur, buf[k]);
        #pragma unroll
        for (int k = 0; k < GW; ++k) buf[k] = nxt[k];
    }
    #pragma unroll
    for (int k = 0; k < GW; ++k) cur = __fadd_rn(cur, buf[k]);
    return cur;
}

// Sum of active rows, LDS path (wave 7, cl = tid-448): same depth-2 shape,
// data from the 64-column LDS slice (banks cl%32, 2-way aliasing = free).
__device__ __forceinline__ float row_sum_lds(const float* __restrict__ Wlds,
                                             const int* __restrict__ act,
                                             int npad, int cl) {
    float cur = 0.f;
    if (npad == 0) return cur;
    int idx[GW];
    float buf[GW];
    #pragma unroll
    for (int q = 0; q < GW / 4; ++q) {
        int4 v = *(const int4*)(&act[q * 4]);
        idx[q * 4] = v.x; idx[q * 4 + 1] = v.y; idx[q * 4 + 2] = v.z; idx[q * 4 + 3] = v.w;
    }
    #pragma unroll
    for (int k = 0; k < GW; ++k) buf[k] = Wlds[idx[k] * H_LDS + cl];
    for (int n = GW; n < npad; n += GW) {
        int nidx[GW];
        float nxt[GW];
        #pragma unroll
        for (int q = 0; q < GW / 4; ++q) {
            int4 v = *(const int4*)(&act[n + q * 4]);
            nidx[q * 4] = v.x; nidx[q * 4 + 1] = v.y; nidx[q * 4 + 2] = v.z; nidx[q * 4 + 3] = v.w;
        }
        #pragma unroll
        for (int k = 0; k < GW; ++k) nxt[k] = Wlds[nidx[k] * H_LDS + cl];
        #pragma unroll
        for (int k = 0; k < GW; ++k) cur = __fadd_rn(cur, buf[k]);
        #pragma unroll
        for (int k = 0; k < GW; ++k) buf[k] = nxt[k];
    }
    #pragma unroll
    for (int k = 0; k < GW; ++k) cur = __fadd_rn(cur, buf[k]);
    return cur;
}

// Two-stage pipeline: even blocks = producer (layer0+layer1), odd = consumer
// (layer2+output). Waves 0-6 read weights from L2, wave 7 from the LDS slice.
__launch_bounds__(512, 1)
__global__ void snn_pipe_kernel(const float* __restrict__ x,     // [256,128,96]
                                const float* __restrict__ Wout,  // [2,512]
                                const float* __restrict__ betas, // [3]
                                const float* __restrict__ thrs,  // [3]
                                const float* __restrict__ W0T,   // [96,512]
                                const float* __restrict__ W1T,   // [513,512]
                                const float* __restrict__ W2T,   // [513,512]
                                unsigned long long* __restrict__ zbuf,
                                int* __restrict__ ctr,
                                float* __restrict__ out)         // [256,128,2]
{
    const int b    = blockIdx.x >> 1;
    const int role = blockIdx.x & 1;
    const int tid  = threadIdx.x;
    const int lane = tid & 63;
    const int wid  = tid >> 6;

    __shared__ float xs[IN_DIM];
    __shared__ unsigned long long zm[8];
    __shared__ alignas(16) int act[HIDDEN + GW];
    __shared__ float red[16];
    extern __shared__ float Wlds[];   // [513][H_LDS]: cols 448..511 (row 512 = zeros)

    // one-time fill of the LDS slice from this role's matrix (incl. zero row)
    {
        const float* Wsrc = (role == 0) ? W1T : W2T;
        const float4* src4 = (const float4*)Wsrc;
        float4* dst4 = (float4*)Wlds;
        for (int idx = tid; idx < WROWS * (H_LDS / 4); idx += 512) {
            int j  = idx >> 4;        // row
            int c4 = idx & 15;        // float4 within the 64-col slice
            dst4[idx] = src4[j * (HIDDEN / 4) + (H_GLB / 4) + c4];
        }
    }
    __syncthreads();

    if (role == 0) {
        // ---------------- producer: layer0 + layer1 ----------------
        const float beta0 = betas[0], beta1 = betas[1];
        const float thr0  = thrs[0],  thr1  = thrs[1];
        float mem0 = 0.f, mem1 = 0.f;
        unsigned long long* zb = zbuf + (size_t)b * T_TOTAL * 8;

        for (int i = 0; i < SEQ_LEN; ++i) {
            if (tid < IN_DIM) xs[tid] = x[(i * BATCH + b) * IN_DIM + tid];
            __syncthreads();

            float cur0 = 0.f;
            #pragma unroll 8
            for (int k = 0; k < IN_DIM; ++k)
                cur0 = __fmaf_rn(xs[k], W0T[k * HIDDEN + tid], cur0);

            for (int s = 0; s < SPIKE_STEPS; ++s) {
                const int t = i * SPIKE_STEPS + s;

                // layer 0 LIF
                bool reset0 = (mem0 - thr0) > 0.f;
                mem0 = reset0 ? 0.f : __fadd_rn(__fmul_rn(beta0, mem0), cur0);
                bool z0 = (mem0 - thr0) > 0.f;
                unsigned long long bal = __ballot(z0);
                if (lane == 0) zm[wid] = bal;
                __syncthreads();

                int nact, npad;
                {
                    int pre = 0, total = 0;
                    #pragma unroll
                    for (int q = 0; q < 8; ++q) {
                        int p = __popcll(zm[q]);
                        total += p;
                        if (q < wid) pre += p;
                    }
                    int rank = pre + __popcll(zm[wid] & ((1ull << lane) - 1ull));
                    if (z0) act[rank] = tid;
                    nact = total;
                    npad = (nact + GW - 1) & ~(GW - 1);
                    if (tid < npad - nact) act[nact + tid] = HIDDEN;  // zero-row pads
                }
                __syncthreads();

                float cur1 = (tid < H_GLB)
                    ? row_sum_glb(W1T, act, npad, tid)
                    : row_sum_lds(Wlds, act, npad, tid - H_GLB);

                // layer 1 LIF
                bool reset1 = (mem1 - thr1) > 0.f;
                mem1 = reset1 ? 0.f : __fadd_rn(__fmul_rn(beta1, mem1), cur1);
                bool z1 = (mem1 - thr1) > 0.f;

                unsigned long long bal1 = __ballot(z1);
                if (lane == 0)
                    __hip_atomic_store(&zb[(size_t)t * 8 + wid], bal1,
                                       __ATOMIC_RELAXED, __HIP_MEMORY_SCOPE_AGENT);
                __syncthreads();   // vmcnt(0) drain before barrier => masks visible
                if (tid == 0)
                    __hip_atomic_store(&ctr[b], t + 1,
                                       __ATOMIC_RELAXED, __HIP_MEMORY_SCOPE_AGENT);
            }
        }
    } else {
        // ---------------- consumer: layer2 + output ----------------
        const float beta2 = betas[2];
        const float thr2  = thrs[2];
        const float wo0 = Wout[tid];
        const float wo1 = Wout[HIDDEN + tid];
        float mem2 = 0.f, mo0 = 0.f, mo1 = 0.f;
        const unsigned long long* zb = zbuf + (size_t)b * T_TOTAL * 8;

        for (int i = 0; i < SEQ_LEN; ++i) {
            float so0 = 0.f, so1 = 0.f;

            for (int s = 0; s < SPIKE_STEPS; ++s) {
                const int t = i * SPIKE_STEPS + s;

                if (tid == 0) {
                    while (__hip_atomic_load(&ctr[b], __ATOMIC_RELAXED,
                                             __HIP_MEMORY_SCOPE_AGENT) < t + 1)
                        __builtin_amdgcn_s_sleep(1);
                }
                __syncthreads();

                if (tid < 8)
                    zm[tid] = __hip_atomic_load(&zb[(size_t)t * 8 + tid],
                                                __ATOMIC_RELAXED, __HIP_MEMORY_SCOPE_AGENT);
                __syncthreads();

                bool z1 = (zm[wid] >> lane) & 1ull;
                int nact, npad;
                {
                    int pre = 0, total = 0;
                    #pragma unroll
                    for (int q = 0; q < 8; ++q) {
                        int p = __popcll(zm[q]);
                        total += p;
                        if (q < wid) pre += p;
                    }
                    int rank = pre + __popcll(zm[wid] & ((1ull << lane) - 1ull));
                    if (z1) act[rank] = tid;
                    nact = total;
                    npad = (nact + GW - 1) & ~(GW - 1);
                    if (tid < npad - nact) act[nact + tid] = HIDDEN;  // zero-row pads
                }
                __syncthreads();

                float cur2 = (tid < H_GLB)
                    ? row_sum_glb(W2T, act, npad, tid)
                    : row_sum_lds(Wlds, act, npad, tid - H_GLB);

                // layer 2 LIF
                bool reset2 = (mem2 - thr2) > 0.f;
                mem2 = reset2 ? 0.f : __fadd_rn(__fmul_rn(beta2, mem2), cur2);
                bool z2 = (mem2 - thr2) > 0.f;

                // output integrator
                float c0 = z2 ? wo0 : 0.f;
                float c1 = z2 ? wo1 : 0.f;
                #pragma unroll
                for (int off = 32; off > 0; off >>= 1) {
                    c0 += __shfl_down(c0, off);
                    c1 += __shfl_down(c1, off);
                }
                if (lane == 0) { red[wid * 2] = c0; red[wid * 2 + 1] = c1; }
                __syncthreads();
                if (tid == 0) {
                    float r0 = 0.f, r1 = 0.f;
                    #pragma unroll
                    for (int q = 0; q < 8; ++q) { r0 += red[q * 2]; r1 += red[q * 2 + 1]; }
                    mo0 += r0; mo1 += r1;
                    so0 += mo0; so1 += mo1;
                }
            }

            if (tid == 0) {
                out[(i * BATCH + b) * OUT_DIM + 0] = so0 / 7.0f;
                out[(i * BATCH + b) * OUT_DIM + 1] = so1 / 7.0f;
            }
        }
    }
}

extern "C" void kernel_launch(void* const* d_in, const int* in_sizes, int n_in,
                              void* d_out, int out_size, void* d_ws, size_t ws_size,
                              hipStream_t stream) {
    const float* x     = (const float*)d_in[0];
    const float* W0    = (const float*)d_in[1];
    const float* W1    = (const float*)d_in[2];
    const float* W2    = (const float*)d_in[3];
    const float* Wout  = (const float*)d_in[4];
    const float* betas = (const float*)d_in[5];
    const float* thrs  = (const float*)d_in[6];
    float* out = (float*)d_out;

    float* ws  = (float*)d_ws;
    float* W0T = ws + W0T_OFF;
    float* W1T = ws + W1T_OFF;
    float* W2T = ws + W2T_OFF;
    int* ctr = (int*)((char*)d_ws + CTR_BYTE_OFF);
    unsigned long long* zbuf = (unsigned long long*)((char*)d_ws + ZBUF_BYTE_OFF);

    // opt-in for >64 KB dynamic LDS (host-side attribute; safe under capture)
    (void)hipFuncSetAttribute((const void*)snn_pipe_kernel,
                              hipFuncAttributeMaxDynamicSharedMemorySize,
                              LDS_DYN_BYTES);

    {
        int n = HIDDEN * IN_DIM;
        transpose_kernel<<<(n + 255) / 256, 256, 0, stream>>>(W0, W0T, HIDDEN, IN_DIM);
    }
    {
        int n = HIDDEN * HIDDEN;
        transpose_kernel<<<(n + 255) / 256, 256, 0, stream>>>(W1, W1T, HIDDEN, HIDDEN);
        transpose_kernel<<<(n + 255) / 256, 256, 0, stream>>>(W2, W2T, HIDDEN, HIDDEN);
    }

    // zero the pad row (index 512) of W1T/W2T, and the progress counters
    hipMemsetAsync(W1T + (size_t)HIDDEN * HIDDEN, 0, HIDDEN * sizeof(float), stream);
    hipMemsetAsync(W2T + (size_t)HIDDEN * HIDDEN, 0, HIDDEN * sizeof(float), stream);
    hipMemsetAsync((char*)d_ws + CTR_BYTE_OFF, 0, 1024, stream);

    snn_pipe_kernel<<<2 * BATCH, HIDDEN, LDS_DYN_BYTES, stream>>>(
        x, Wout, betas, thrs, W0T, W1T, W2T, zbuf, ctr, out);
}